// Round 1
// 448.105 us; speedup vs baseline: 1.4697x; 1.4697x over previous
//
#include <hip/hip_runtime.h>
#include <cmath>

typedef unsigned long long u64;

#define PRE_TOPN 12000
#define POST_TOPN 2000
#define SORTN 32768
#define TILE 8192
#define NTILE (SORTN / TILE)   // 4 tiles per batch
#define NBLK 188               // 64-bit column blocks covering 12032
#define PADN (NBLK * 64)       // 12032
// triangular bitmap: column-block cb stores rows 0..(cb+1)*64-1
// triOff(cb) = 32*cb*(cb+1); total words per batch:
#define TRI_WORDS (32 * (NBLK - 1) * NBLK + NBLK * 64)  // 1,137,024

__device__ inline u64 shfl_u64(u64 v, int lane) {
    int lo = __shfl((int)(unsigned)(v & 0xffffffffULL), lane);
    int hi = __shfl((int)(unsigned)(v >> 32), lane);
    return ((u64)(unsigned)hi << 32) | (u64)(unsigned)lo;
}

__device__ inline u64 shfl_xor_u64(u64 v, int mask) {
    int lo = __shfl_xor((int)(unsigned)(v & 0xffffffffULL), mask);
    int hi = __shfl_xor((int)(unsigned)(v >> 32), mask);
    return ((u64)(unsigned)hi << 32) | (u64)(unsigned)lo;
}

// ---------------------------------------------------------------------------
// Kernel 1: decode boxes (exact fp32 op order, no FMA contraction, exp via
// double) and pack sort keys. key = (~score_bits)<<32 | idx.
// Also resets the per-batch NMS progress state (kcnt/done) for this launch.
// ---------------------------------------------------------------------------
__global__ void decode_pack(const float* __restrict__ anchors,
                            const float* __restrict__ deltas,
                            const float* __restrict__ scores,
                            float* __restrict__ boxes,
                            u64* __restrict__ keys,
                            int* __restrict__ kcnt,
                            int* __restrict__ done,
                            int N) {
#pragma clang fp contract(off)
    int n = blockIdx.x * blockDim.x + threadIdx.x;
    int b = blockIdx.y;
    if (kcnt != nullptr && blockIdx.x == 0 && threadIdx.x == 0) {
        kcnt[b] = 0;
        done[b] = 0;
    }
    if (n >= SORTN) return;
    u64* kb = keys + (size_t)b * SORTN;
    if (n < N) {
        float a0 = anchors[n * 4 + 0];
        float a1 = anchors[n * 4 + 1];
        float a2 = anchors[n * 4 + 2];
        float a3 = anchors[n * 4 + 3];
        float w = (a2 - a0) + 1.0f;
        float h = (a3 - a1) + 1.0f;
        float cx = a0 + 0.5f * w;
        float cy = a1 + 0.5f * h;
        const float* d = deltas + ((size_t)b * N + n) * 4;
        float dx = d[0], dy = d[1], dw = d[2], dh = d[3];
        float px = cx + w * dx;
        float py = cy + h * dy;
        float pw = (float)::exp((double)dw) * w;
        float ph = (float)::exp((double)dh) * h;
        float* bb = boxes + ((size_t)b * N + n) * 4;
        bb[0] = px - 0.5f * pw;
        bb[1] = py - 0.5f * ph;
        bb[2] = px + 0.5f * (pw - 2.0f);
        bb[3] = py + 0.5f * (ph - 2.0f);
        unsigned int sb = __float_as_uint(scores[(size_t)b * N + n]);
        kb[n] = ((u64)(~sb) << 32) | (u64)(unsigned int)n;
    } else {
        kb[n] = ~0ULL;
    }
}

// ---------------------------------------------------------------------------
// Hybrid bitonic sort (unchanged).
// ---------------------------------------------------------------------------
__global__ __launch_bounds__(1024) void bitonic_local_sort(u64* __restrict__ keys) {
    __shared__ u64 sk[TILE];
    int tile = blockIdx.x;
    u64* kb = keys + (size_t)tile * TILE;
    int base = (tile % NTILE) * TILE;
    for (int i = threadIdx.x; i < TILE; i += 1024) sk[i] = kb[i];
    __syncthreads();
    for (int k = 2; k <= TILE; k <<= 1) {
        for (int j = k >> 1; j > 0; j >>= 1) {
            for (int t = threadIdx.x; t < TILE / 2; t += 1024) {
                int i = ((t & ~(j - 1)) << 1) | (t & (j - 1));
                int ixj = i | j;
                u64 a = sk[i];
                u64 c = sk[ixj];
                bool up = (((base + i) & k) == 0);
                if ((a > c) == up) { sk[i] = c; sk[ixj] = a; }
            }
            __syncthreads();
        }
    }
    for (int i = threadIdx.x; i < TILE; i += 1024) kb[i] = sk[i];
}

__global__ void bitonic_global_step(u64* __restrict__ keys, int k, int j) {
    int t = blockIdx.x * blockDim.x + threadIdx.x;
    int b = t / (SORTN / 2);
    int s = t % (SORTN / 2);
    int i = ((s & ~(j - 1)) << 1) | (s & (j - 1));
    int ixj = i | j;
    u64* kb = keys + (size_t)b * SORTN;
    u64 a = kb[i];
    u64 c = kb[ixj];
    bool up = ((i & k) == 0);
    if ((a > c) == up) { kb[i] = c; kb[ixj] = a; }
}

__global__ __launch_bounds__(1024) void bitonic_local_merge(u64* __restrict__ keys, int k) {
    __shared__ u64 sk[TILE];
    int tile = blockIdx.x;
    u64* kb = keys + (size_t)tile * TILE;
    int base = (tile % NTILE) * TILE;
    bool up = ((base & k) == 0);
    for (int i = threadIdx.x; i < TILE; i += 1024) sk[i] = kb[i];
    __syncthreads();
    for (int j = TILE / 2; j > 0; j >>= 1) {
        for (int t = threadIdx.x; t < TILE / 2; t += 1024) {
            int i = ((t & ~(j - 1)) << 1) | (t & (j - 1));
            int ixj = i | j;
            u64 a = sk[i];
            u64 c = sk[ixj];
            if ((a > c) == up) { sk[i] = c; sk[ixj] = a; }
        }
        __syncthreads();
    }
    for (int i = threadIdx.x; i < TILE; i += 1024) kb[i] = sk[i];
}

// ---------------------------------------------------------------------------
// Gather sorted top-PADN boxes. Pad rows get far-away degenerate boxes.
// ---------------------------------------------------------------------------
__global__ void gather_sorted(const float* __restrict__ boxes,
                              const u64* __restrict__ keys,
                              float4* __restrict__ sbox, int N) {
    int r = blockIdx.x * 256 + threadIdx.x;
    int b = blockIdx.y;
    if (r >= PADN) return;
    float4 v;
    if (r < PRE_TOPN) {
        u64 key = keys[(size_t)b * SORTN + r];
        int n = (int)(unsigned)(key & 0xffffffffULL);
        v = ((const float4*)boxes)[(size_t)b * N + n];
    } else {
        v = make_float4(-4e8f, -4e8f, -4e8f, -4e8f);
    }
    sbox[(size_t)b * PADN + r] = v;
}

// ---------------------------------------------------------------------------
// Exact-f32 suppression predicate (bit-identical to the f64 reference test).
// Condition (round-5 proof): RN_f32(inter/un) > 0.7f  <=>  inter >= M*un
// with M = 0.7f + 2^-25 (exact real). Fast path:
//   t   = RN(inter - 0.7f*un)   (one fma, single rounding of D)
//   u25 = un * 2^-25            (exact: un >= ~20, power-of-2 scale)
// RN is monotone and u25 is representable, so:
//   t > u25  ==>  D > u25  (suppress),  t < u25  ==>  D < u25  (keep),
//   t == u25 ==>  ambiguous (half-ulp band) -> rare exact-f64 redo of the row.
// ---------------------------------------------------------------------------
__device__ __forceinline__ void iou_bit(float4 me, float ar, float4 cj, float aj,
                                        int j, unsigned& lo, unsigned& hi, int& tie) {
#pragma clang fp contract(off)
    float xx1 = fmaxf(me.x, cj.x);
    float yy1 = fmaxf(me.y, cj.y);
    float xx2 = fminf(me.z, cj.z);
    float yy2 = fminf(me.w, cj.w);
    float w = fmaxf((xx2 - xx1) + 1.0f, 0.0f);
    float h = fmaxf((yy2 - yy1) + 1.0f, 0.0f);
    float inter = w * h;
    float un = (ar + aj) - inter;
    float t = __builtin_fmaf(-0.7f, un, inter);
    float u25 = un * 0x1p-25f;
    unsigned sup = (t > u25) ? 1u : 0u;
    tie |= (t == u25) ? 1 : 0;
    if (j < 32) lo |= sup << j;
    else        hi |= sup << (j - 32);
}

__device__ __attribute__((noinline)) u64 slow_word(float4 me, float ar,
                                                   const float4* cbox,
                                                   const float* carea) {
#pragma clang fp contract(off)
    const double MD = (double)0.7f + 0x1p-25;   // exact midpoint multiplier
    u64 word = 0;
    for (int j = 0; j < 64; ++j) {
        float4 cj = cbox[j];
        float aj = carea[j];
        float xx1 = fmaxf(me.x, cj.x);
        float yy1 = fmaxf(me.y, cj.y);
        float xx2 = fminf(me.z, cj.z);
        float yy2 = fminf(me.w, cj.w);
        float w = fmaxf((xx2 - xx1) + 1.0f, 0.0f);
        float h = fmaxf((yy2 - yy1) + 1.0f, 0.0f);
        float inter = w * h;
        float un = (ar + aj) - inter;
        bool sup = ((double)inter >= MD * (double)un);
        word |= ((u64)sup) << j;
    }
    return word;
}

// ---------------------------------------------------------------------------
// Build suppression bitmap for column blocks [cb0, cb0+gridDim.x).
// Two rows per thread (512-row chunks): one LDS broadcast pair feeds 2 IoUs.
// Per-batch done[] flag lets completed batches skip all remaining stages.
// ---------------------------------------------------------------------------
__global__ __launch_bounds__(256) void build_bitmap(const float4* __restrict__ sbox,
                                                    u64* __restrict__ bitmap,
                                                    const int* __restrict__ done,
                                                    int cb0) {
    int cb = cb0 + blockIdx.x;  // column block
    int chunk = blockIdx.y;     // row chunk (512 rows)
    int b = blockIdx.z;
    if (done[b]) return;
    if (chunk * 8 > cb) return; // chunk's first row >= (cb+1)*64 -> empty
    int tid = threadIdx.x;
    int lim = (cb + 1) * 64;    // rows stored in this slab: [0, lim)

    __shared__ float4 cbox[64];
    __shared__ float carea[64];
    const float4* sb = sbox + (size_t)b * PADN;
    if (tid < 64) {
        float4 c4 = sb[cb * 64 + tid];
        cbox[tid] = c4;
        carea[tid] = ((c4.z - c4.x) + 1.0f) * ((c4.w - c4.y) + 1.0f);
    }
    int r1 = chunk * 512 + tid;        // <= 12031 always (chunk<=23 under guard)
    int r2 = r1 + 256;
    bool a1 = (r1 < lim);              // wave-uniform (lim % 64 == 0)
    bool a2 = (r2 < lim);              // implies r2 < PADN
    float4 me1 = sb[r1];
    float4 me2 = me1;
    if (a2) me2 = sb[r2];
    float ar1 = ((me1.z - me1.x) + 1.0f) * ((me1.w - me1.y) + 1.0f);
    float ar2 = ((me2.z - me2.x) + 1.0f) * ((me2.w - me2.y) + 1.0f);
    __syncthreads();

    u64* dst = bitmap + (size_t)b * TRI_WORDS + (size_t)32 * cb * (cb + 1);
    if (a2) {
        unsigned lo1 = 0, hi1 = 0, lo2 = 0, hi2 = 0;
        int tie1 = 0, tie2 = 0;
#pragma unroll
        for (int j = 0; j < 64; ++j) {
            float4 cj = cbox[j];
            float aj = carea[j];
            iou_bit(me1, ar1, cj, aj, j, lo1, hi1, tie1);
            iou_bit(me2, ar2, cj, aj, j, lo2, hi2, tie2);
        }
        u64 w1 = ((u64)hi1 << 32) | lo1;
        u64 w2 = ((u64)hi2 << 32) | lo2;
        if (__builtin_expect(tie1, 0)) w1 = slow_word(me1, ar1, cbox, carea);
        if (__builtin_expect(tie2, 0)) w2 = slow_word(me2, ar2, cbox, carea);
        int d1 = r1 - cb * 64;
        if (d1 >= 0) w1 &= ~((2ULL << d1) - 1ULL);   // keep cols strictly after row
        int d2 = r2 - cb * 64;
        if (d2 >= 0) w2 &= ~((2ULL << d2) - 1ULL);
        dst[r1] = w1;
        dst[r2] = w2;
    } else if (a1) {
        unsigned lo1 = 0, hi1 = 0;
        int tie1 = 0;
#pragma unroll
        for (int j = 0; j < 64; ++j) {
            float4 cj = cbox[j];
            float aj = carea[j];
            iou_bit(me1, ar1, cj, aj, j, lo1, hi1, tie1);
        }
        u64 w1 = ((u64)hi1 << 32) | lo1;
        if (__builtin_expect(tie1, 0)) w1 = slow_word(me1, ar1, cbox, carea);
        int d1 = r1 - cb * 64;
        if (d1 >= 0) w1 &= ~((2ULL << d1) - 1ULL);
        dst[r1] = w1;
    }
}

// ---------------------------------------------------------------------------
// Resumable sequential scan stage: processes column blocks [rb0, rb1).
// State persisted in workspace: picks_g (global pick rows), kcnt, done.
// Semantics identical to the single-pass round-6 scan; splitting the rb loop
// across launches lets build_bitmap run progressively so that column blocks
// past the 2000-picks completion point are never built.
// ---------------------------------------------------------------------------
__global__ __launch_bounds__(256) void scan_nms(const float4* __restrict__ sbox,
                                                const u64* __restrict__ bitmap,
                                                float* __restrict__ out,
                                                int* __restrict__ picks_g,
                                                int* __restrict__ kcnt,
                                                int* __restrict__ done,
                                                int rb0, int rb1) {
    int b = blockIdx.x;
    if (done[b]) return;
    int tid = threadIdx.x;
    int lane = tid & 63;
    int wv = tid >> 6;
    __shared__ int picks_lds[POST_TOPN];   // 8 KB
    __shared__ u64 s_partial[4];
    __shared__ int s_K;

    int* pg = picks_g + (size_t)b * POST_TOPN;
    int K0 = kcnt[b];
    if (tid == 0) s_K = K0;
    for (int t = tid; t < K0; t += 256) picks_lds[t] = pg[t];
    __syncthreads();

    const u64* bm = bitmap + (size_t)b * TRI_WORDS;

    for (int rb = rb0; rb < rb1; ++rb) {
        int K = s_K;                       // uniform (post-barrier)
        if (K >= POST_TOPN) break;
        const u64* slab = bm + (size_t)32 * rb * (rb + 1);  // rows 0..(rb+1)*64-1
        int base = rb * 64;

        // wave-0 prefetch (issues before the gather's waits)
        u64 myrow = 0;
        float4 mybox = make_float4(0.f, 0.f, 0.f, 0.f);
        if (wv == 0) {
            myrow = slab[base + lane];
            mybox = sbox[(size_t)b * PADN + base + lane];
        }

        // deferred gather: OR suppression words of all prior picks
        u64 sup = 0;
        {
            int t = tid;
            for (; t + 768 < K; t += 1024) {
                u64 w0 = slab[picks_lds[t]];
                u64 w1 = slab[picks_lds[t + 256]];
                u64 w2 = slab[picks_lds[t + 512]];
                u64 w3 = slab[picks_lds[t + 768]];
                sup |= (w0 | w1) | (w2 | w3);
            }
            for (; t < K; t += 256) sup |= slab[picks_lds[t]];
        }
        // 64-lane butterfly OR-reduce, then cross-wave partials
        for (int off = 1; off < 64; off <<= 1) sup |= shfl_xor_u64(sup, off);
        if (lane == 0) s_partial[wv] = sup;
        __syncthreads();

        if (wv == 0) {
            u64 total = s_partial[0] | s_partial[1] | s_partial[2] | s_partial[3];
            if (rb == NBLK - 1) total |= 0xFFFFFFFF00000000ULL;   // pad rows >= 12000
            int c = lane;
            u64 alive = ~total;
            u64 picks = 0;
            u64 cur = alive;
            while (cur) {
                int i = __ffsll((long long)cur) - 1;
                picks |= 1ULL << i;
                u64 row = shfl_u64(myrow, i);
                alive &= ~row;
                cur = alive & ~((2ULL << i) - 1ULL);
            }
            int avail = POST_TOPN - K;
            int np = __popcll(picks);
            while (np > avail) {                       // truncate latest picks
                picks &= ~(1ULL << (63 - __clzll(picks)));
                --np;
            }
            if ((picks >> c) & 1ULL) {
                int rank = __popcll(picks & ((1ULL << c) - 1ULL));
                int gi = base + c;
                picks_lds[K + rank] = gi;
                pg[K + rank] = gi;
                float* o = out + ((size_t)b * POST_TOPN + K + rank) * 5;
                o[0] = (float)b; o[1] = mybox.x; o[2] = mybox.y; o[3] = mybox.z; o[4] = mybox.w;
            }
            if (c == 0) s_K = K + np;
        }
        __syncthreads();
    }

    int K = s_K;
    if (K >= POST_TOPN || rb1 >= NBLK) {
        for (int r = K + tid; r < POST_TOPN; r += 256) {
            float* o = out + ((size_t)b * POST_TOPN + r) * 5;
            o[0] = 0.0f; o[1] = 0.0f; o[2] = 0.0f; o[3] = 0.0f; o[4] = 0.0f;
        }
        if (tid == 0) done[b] = 1;
    }
    if (tid == 0) kcnt[b] = K;
}

// ---------------------------------------------------------------------------
// Fallback (round-2) NMS kernel — used only if ws_size can't hold the bitmap.
// ---------------------------------------------------------------------------
__global__ __launch_bounds__(1024) void nms_kernel(const float* __restrict__ boxes,
                                                   const u64* __restrict__ keys,
                                                   float* __restrict__ out,
                                                   int N) {
#pragma clang fp contract(off)
    __shared__ float4 kbox[POST_TOPN];
    __shared__ float kar[POST_TOPN];
    __shared__ float4 cbox[64];
    __shared__ float car_s[64];
    __shared__ int supp[64];
    __shared__ int s_cnt;

    int b = blockIdx.x;
    int tid = threadIdx.x;
    const u64* kb = keys + (size_t)b * SORTN;
    const float* bb = boxes + (size_t)b * N * 4;

    if (tid == 0) s_cnt = 0;
    __syncthreads();

    for (int start = 0; start < PRE_TOPN; start += 64) {
        int K = s_cnt;
        if (K >= POST_TOPN) break;
        int csize = min(64, PRE_TOPN - start);

        if (tid < 64) {
            int c = tid;
            if (c < csize) {
                u64 key = kb[start + c];
                int n = (int)(unsigned int)(key & 0xFFFFFFFFULL);
                const float* p = bb + (size_t)n * 4;
                float x1 = p[0], y1 = p[1], x2 = p[2], y2 = p[3];
                cbox[c] = make_float4(x1, y1, x2, y2);
                car_s[c] = ((x2 - x1) + 1.0f) * ((y2 - y1) + 1.0f);
            }
            supp[c] = 0;
        }
        __syncthreads();

        {
            int c = tid & 63;
            int sl = tid >> 6;
            if (c < csize) {
                float4 me = cbox[c];
                float ar = car_s[c];
                int flag = 0;
                for (int kk = sl; kk < K; kk += 16) {
                    float4 k0 = kbox[kk];
                    float a0 = kar[kk];
                    float xx1 = fmaxf(k0.x, me.x);
                    float yy1 = fmaxf(k0.y, me.y);
                    float xx2 = fminf(k0.z, me.z);
                    float yy2 = fminf(k0.w, me.w);
                    float w0 = fmaxf((xx2 - xx1) + 1.0f, 0.0f);
                    float h0 = fmaxf((yy2 - yy1) + 1.0f, 0.0f);
                    float inter0 = w0 * h0;
                    float iou0 = inter0 / ((a0 + ar) - inter0);
                    if (iou0 > 0.7f) { flag = 1; break; }
                }
                if (flag) supp[c] = 1;
            }
        }
        __syncthreads();

        if (tid < 64) {
            int c = tid;
            bool alive = (c < csize) && (supp[c] == 0);
            float4 me = cbox[c];
            float ar = car_s[c];
            int cnt = K;
            u64 m = __ballot(alive);
            while (m != 0 && cnt < POST_TOPN) {
                int i = __ffsll((unsigned long long)m) - 1;
                float ix1 = __shfl(me.x, i);
                float iy1 = __shfl(me.y, i);
                float ix2 = __shfl(me.z, i);
                float iy2 = __shfl(me.w, i);
                float iar = __shfl(ar, i);
                if (c == i) {
                    kbox[cnt] = me;
                    kar[cnt] = ar;
                    float* o = out + ((size_t)b * POST_TOPN + cnt) * 5;
                    o[0] = (float)b; o[1] = me.x; o[2] = me.y; o[3] = me.z; o[4] = me.w;
                }
                if (alive && c > i) {
                    float xx1 = fmaxf(ix1, me.x);
                    float yy1 = fmaxf(iy1, me.y);
                    float xx2 = fminf(ix2, me.z);
                    float yy2 = fminf(iy2, me.w);
                    float w = fmaxf((xx2 - xx1) + 1.0f, 0.0f);
                    float h = fmaxf((yy2 - yy1) + 1.0f, 0.0f);
                    float inter = w * h;
                    float iou = inter / ((iar + ar) - inter);
                    if (iou > 0.7f) alive = false;
                }
                cnt++;
                m = __ballot(alive);
                u64 clearmask = (2ULL << i) - 1ULL;
                m &= ~clearmask;
            }
            if (c == 0) s_cnt = cnt;
        }
        __syncthreads();
    }

    __syncthreads();
    int K = s_cnt;
    for (int r = K + tid; r < POST_TOPN; r += (int)blockDim.x) {
        float* o = out + ((size_t)b * POST_TOPN + r) * 5;
        o[0] = 0.0f; o[1] = 0.0f; o[2] = 0.0f; o[3] = 0.0f; o[4] = 0.0f;
    }
}

// ---------------------------------------------------------------------------
extern "C" void kernel_launch(void* const* d_in, const int* in_sizes, int n_in,
                              void* d_out, int out_size, void* d_ws, size_t ws_size,
                              hipStream_t stream) {
    const float* anchors = (const float*)d_in[0];
    const float* deltas  = (const float*)d_in[1];
    const float* scores  = (const float*)d_in[2];
    float* out = (float*)d_out;

    int N = in_sizes[0] / 4;           // 27380
    int B = in_sizes[2] / N;           // 8

    size_t off = 0;
    auto take = [&](size_t bytes) { size_t o = off; off = (off + bytes + 255) & ~(size_t)255; return o; };
    size_t boxesOff  = take((size_t)B * N * 4 * sizeof(float));
    size_t keysOff   = take((size_t)B * SORTN * sizeof(u64));
    size_t sboxOff   = take((size_t)B * PADN * sizeof(float4));
    size_t bitmapOff = take((size_t)B * TRI_WORDS * sizeof(u64));
    size_t picksOff  = take((size_t)B * POST_TOPN * sizeof(int));
    size_t kcntOff   = take((size_t)B * sizeof(int));
    size_t doneOff   = take((size_t)B * sizeof(int));
    bool bitmap_path = (off <= ws_size);

    float* boxes = (float*)((char*)d_ws + boxesOff);
    u64*   keys  = (u64*)((char*)d_ws + keysOff);
    int* picks_g = bitmap_path ? (int*)((char*)d_ws + picksOff) : nullptr;
    int* kcnt    = bitmap_path ? (int*)((char*)d_ws + kcntOff)  : nullptr;
    int* done    = bitmap_path ? (int*)((char*)d_ws + doneOff)  : nullptr;

    dim3 g1((unsigned)((SORTN + 255) / 256), (unsigned)B);
    decode_pack<<<g1, 256, 0, stream>>>(anchors, deltas, scores, boxes, keys, kcnt, done, N);

    int ntiles = B * NTILE;
    bitonic_local_sort<<<ntiles, 1024, 0, stream>>>(keys);
    int gsteps = B * (SORTN / 2) / 256;
    bitonic_global_step<<<gsteps, 256, 0, stream>>>(keys, 2 * TILE, TILE);
    bitonic_local_merge<<<ntiles, 1024, 0, stream>>>(keys, 2 * TILE);
    bitonic_global_step<<<gsteps, 256, 0, stream>>>(keys, 4 * TILE, 2 * TILE);
    bitonic_global_step<<<gsteps, 256, 0, stream>>>(keys, 4 * TILE, TILE);
    bitonic_local_merge<<<ntiles, 1024, 0, stream>>>(keys, 4 * TILE);

    if (bitmap_path) {
        float4* sbox = (float4*)((char*)d_ws + sboxOff);
        u64* bitmap  = (u64*)((char*)d_ws + bitmapOff);
        dim3 gg((unsigned)((PADN + 255) / 256), (unsigned)B);
        gather_sorted<<<gg, 256, 0, stream>>>(boxes, keys, sbox, N);

        // Progressive build/scan: each scan stage consumes the column blocks
        // built so far; once a batch reaches 2000 picks its done[] flag makes
        // all later build/scan blocks exit immediately. Final stage always
        // reaches NBLK, so correctness is independent of the pick rate.
        const int seg[6] = {0, 48, 64, 88, 120, NBLK};
        for (int s = 0; s < 5; ++s) {
            int c0 = seg[s], c1 = seg[s + 1];
            unsigned gy = (unsigned)(((c1 - 1) >> 3) + 1);   // 512-row chunks
            dim3 gb((unsigned)(c1 - c0), gy, (unsigned)B);
            build_bitmap<<<gb, 256, 0, stream>>>(sbox, bitmap, done, c0);
            scan_nms<<<B, 256, 0, stream>>>(sbox, bitmap, out, picks_g, kcnt, done, c0, c1);
        }
    } else {
        nms_kernel<<<B, 1024, 0, stream>>>(boxes, keys, out, N);
    }
}

// Round 2
// 354.526 us; speedup vs baseline: 1.8577x; 1.2640x over previous
//
#include <hip/hip_runtime.h>
#include <cmath>

typedef unsigned long long u64;

#define PRE_TOPN 12000
#define POST_TOPN 2000
#define SORTN 32768
#define TILE 8192
#define NTILE (SORTN / TILE)   // 4 tiles per batch
#define NBLK 188               // 64-bit column blocks covering 12032
#define PADN (NBLK * 64)       // 12032
// triangular bitmap: column-block cb stores rows 0..(cb+1)*64-1
// triOff(cb) = 32*cb*(cb+1); total words per batch:
#define TRI_WORDS (32 * (NBLK - 1) * NBLK + NBLK * 64)  // 1,137,024

// ---------------------------------------------------------------------------
// Kernel 1: decode boxes (exact fp32 op order, no FMA contraction, exp via
// double) and pack sort keys. key = (~score_bits)<<32 | idx.
// Also resets the per-batch NMS progress state (kcnt/done) for this launch.
// ---------------------------------------------------------------------------
__global__ void decode_pack(const float* __restrict__ anchors,
                            const float* __restrict__ deltas,
                            const float* __restrict__ scores,
                            float* __restrict__ boxes,
                            u64* __restrict__ keys,
                            int* __restrict__ kcnt,
                            int* __restrict__ done,
                            int N) {
#pragma clang fp contract(off)
    int n = blockIdx.x * blockDim.x + threadIdx.x;
    int b = blockIdx.y;
    if (kcnt != nullptr && blockIdx.x == 0 && threadIdx.x == 0) {
        kcnt[b] = 0;
        done[b] = 0;
    }
    if (n >= SORTN) return;
    u64* kb = keys + (size_t)b * SORTN;
    if (n < N) {
        float a0 = anchors[n * 4 + 0];
        float a1 = anchors[n * 4 + 1];
        float a2 = anchors[n * 4 + 2];
        float a3 = anchors[n * 4 + 3];
        float w = (a2 - a0) + 1.0f;
        float h = (a3 - a1) + 1.0f;
        float cx = a0 + 0.5f * w;
        float cy = a1 + 0.5f * h;
        const float* d = deltas + ((size_t)b * N + n) * 4;
        float dx = d[0], dy = d[1], dw = d[2], dh = d[3];
        float px = cx + w * dx;
        float py = cy + h * dy;
        float pw = (float)::exp((double)dw) * w;
        float ph = (float)::exp((double)dh) * h;
        float* bb = boxes + ((size_t)b * N + n) * 4;
        bb[0] = px - 0.5f * pw;
        bb[1] = py - 0.5f * ph;
        bb[2] = px + 0.5f * (pw - 2.0f);
        bb[3] = py + 0.5f * (ph - 2.0f);
        unsigned int sb = __float_as_uint(scores[(size_t)b * N + n]);
        kb[n] = ((u64)(~sb) << 32) | (u64)(unsigned int)n;
    } else {
        kb[n] = ~0ULL;
    }
}

// ---------------------------------------------------------------------------
// Hybrid bitonic sort (unchanged).
// ---------------------------------------------------------------------------
__global__ __launch_bounds__(1024) void bitonic_local_sort(u64* __restrict__ keys) {
    __shared__ u64 sk[TILE];
    int tile = blockIdx.x;
    u64* kb = keys + (size_t)tile * TILE;
    int base = (tile % NTILE) * TILE;
    for (int i = threadIdx.x; i < TILE; i += 1024) sk[i] = kb[i];
    __syncthreads();
    for (int k = 2; k <= TILE; k <<= 1) {
        for (int j = k >> 1; j > 0; j >>= 1) {
            for (int t = threadIdx.x; t < TILE / 2; t += 1024) {
                int i = ((t & ~(j - 1)) << 1) | (t & (j - 1));
                int ixj = i | j;
                u64 a = sk[i];
                u64 c = sk[ixj];
                bool up = (((base + i) & k) == 0);
                if ((a > c) == up) { sk[i] = c; sk[ixj] = a; }
            }
            __syncthreads();
        }
    }
    for (int i = threadIdx.x; i < TILE; i += 1024) kb[i] = sk[i];
}

__global__ void bitonic_global_step(u64* __restrict__ keys, int k, int j) {
    int t = blockIdx.x * blockDim.x + threadIdx.x;
    int b = t / (SORTN / 2);
    int s = t % (SORTN / 2);
    int i = ((s & ~(j - 1)) << 1) | (s & (j - 1));
    int ixj = i | j;
    u64* kb = keys + (size_t)b * SORTN;
    u64 a = kb[i];
    u64 c = kb[ixj];
    bool up = ((i & k) == 0);
    if ((a > c) == up) { kb[i] = c; kb[ixj] = a; }
}

__global__ __launch_bounds__(1024) void bitonic_local_merge(u64* __restrict__ keys, int k) {
    __shared__ u64 sk[TILE];
    int tile = blockIdx.x;
    u64* kb = keys + (size_t)tile * TILE;
    int base = (tile % NTILE) * TILE;
    bool up = ((base & k) == 0);
    for (int i = threadIdx.x; i < TILE; i += 1024) sk[i] = kb[i];
    __syncthreads();
    for (int j = TILE / 2; j > 0; j >>= 1) {
        for (int t = threadIdx.x; t < TILE / 2; t += 1024) {
            int i = ((t & ~(j - 1)) << 1) | (t & (j - 1));
            int ixj = i | j;
            u64 a = sk[i];
            u64 c = sk[ixj];
            if ((a > c) == up) { sk[i] = c; sk[ixj] = a; }
        }
        __syncthreads();
    }
    for (int i = threadIdx.x; i < TILE; i += 1024) kb[i] = sk[i];
}

// ---------------------------------------------------------------------------
// Gather sorted top-PADN boxes. Pad rows get far-away degenerate boxes.
// ---------------------------------------------------------------------------
__global__ void gather_sorted(const float* __restrict__ boxes,
                              const u64* __restrict__ keys,
                              float4* __restrict__ sbox, int N) {
    int r = blockIdx.x * 256 + threadIdx.x;
    int b = blockIdx.y;
    if (r >= PADN) return;
    float4 v;
    if (r < PRE_TOPN) {
        u64 key = keys[(size_t)b * SORTN + r];
        int n = (int)(unsigned)(key & 0xffffffffULL);
        v = ((const float4*)boxes)[(size_t)b * N + n];
    } else {
        v = make_float4(-4e8f, -4e8f, -4e8f, -4e8f);
    }
    sbox[(size_t)b * PADN + r] = v;
}

// ---------------------------------------------------------------------------
// Exact-f32 suppression predicate (bit-identical to the f64 reference test).
// Condition (round-5 proof): RN_f32(inter/un) > 0.7f  <=>  inter >= M*un
// with M = 0.7f + 2^-25 (exact real). Fast path:
//   t   = RN(inter - 0.7f*un)   (one fma, single rounding of D)
//   u25 = un * 2^-25            (exact: un >= ~20, power-of-2 scale)
// RN is monotone and u25 is representable, so:
//   t > u25  ==>  D > u25  (suppress),  t < u25  ==>  D < u25  (keep),
//   t == u25 ==>  ambiguous (half-ulp band) -> rare exact-f64 redo of the row.
// ---------------------------------------------------------------------------
__device__ __forceinline__ void iou_bit(float4 me, float ar, float4 cj, float aj,
                                        int j, unsigned& lo, unsigned& hi, int& tie) {
#pragma clang fp contract(off)
    float xx1 = fmaxf(me.x, cj.x);
    float yy1 = fmaxf(me.y, cj.y);
    float xx2 = fminf(me.z, cj.z);
    float yy2 = fminf(me.w, cj.w);
    float w = fmaxf((xx2 - xx1) + 1.0f, 0.0f);
    float h = fmaxf((yy2 - yy1) + 1.0f, 0.0f);
    float inter = w * h;
    float un = (ar + aj) - inter;
    float t = __builtin_fmaf(-0.7f, un, inter);
    float u25 = un * 0x1p-25f;
    unsigned sup = (t > u25) ? 1u : 0u;
    tie |= (t == u25) ? 1 : 0;
    if (j < 32) lo |= sup << j;
    else        hi |= sup << (j - 32);
}

__device__ __attribute__((noinline)) u64 slow_word(float4 me, float ar,
                                                   const float4* cbox,
                                                   const float* carea) {
#pragma clang fp contract(off)
    const double MD = (double)0.7f + 0x1p-25;   // exact midpoint multiplier
    u64 word = 0;
    for (int j = 0; j < 64; ++j) {
        float4 cj = cbox[j];
        float aj = carea[j];
        float xx1 = fmaxf(me.x, cj.x);
        float yy1 = fmaxf(me.y, cj.y);
        float xx2 = fminf(me.z, cj.z);
        float yy2 = fminf(me.w, cj.w);
        float w = fmaxf((xx2 - xx1) + 1.0f, 0.0f);
        float h = fmaxf((yy2 - yy1) + 1.0f, 0.0f);
        float inter = w * h;
        float un = (ar + aj) - inter;
        bool sup = ((double)inter >= MD * (double)un);
        word |= ((u64)sup) << j;
    }
    return word;
}

// ---------------------------------------------------------------------------
// Build suppression bitmap for column blocks [cb0, cb0+gridDim.x).
// Two rows per thread (512-row chunks): one LDS broadcast pair feeds 2 IoUs.
// Per-batch done[] flag lets completed batches skip all remaining stages.
// ---------------------------------------------------------------------------
__global__ __launch_bounds__(256) void build_bitmap(const float4* __restrict__ sbox,
                                                    u64* __restrict__ bitmap,
                                                    const int* __restrict__ done,
                                                    int cb0) {
    int cb = cb0 + blockIdx.x;  // column block
    int chunk = blockIdx.y;     // row chunk (512 rows)
    int b = blockIdx.z;
    if (done[b]) return;
    if (chunk * 8 > cb) return; // chunk's first row >= (cb+1)*64 -> empty
    int tid = threadIdx.x;
    int lim = (cb + 1) * 64;    // rows stored in this slab: [0, lim)

    __shared__ float4 cbox[64];
    __shared__ float carea[64];
    const float4* sb = sbox + (size_t)b * PADN;
    if (tid < 64) {
        float4 c4 = sb[cb * 64 + tid];
        cbox[tid] = c4;
        carea[tid] = ((c4.z - c4.x) + 1.0f) * ((c4.w - c4.y) + 1.0f);
    }
    int r1 = chunk * 512 + tid;        // <= 12031 always (chunk<=23 under guard)
    int r2 = r1 + 256;
    bool a1 = (r1 < lim);              // wave-uniform (lim % 64 == 0)
    bool a2 = (r2 < lim);              // implies r2 < PADN
    float4 me1 = sb[r1];
    float4 me2 = me1;
    if (a2) me2 = sb[r2];
    float ar1 = ((me1.z - me1.x) + 1.0f) * ((me1.w - me1.y) + 1.0f);
    float ar2 = ((me2.z - me2.x) + 1.0f) * ((me2.w - me2.y) + 1.0f);
    __syncthreads();

    u64* dst = bitmap + (size_t)b * TRI_WORDS + (size_t)32 * cb * (cb + 1);
    if (a2) {
        unsigned lo1 = 0, hi1 = 0, lo2 = 0, hi2 = 0;
        int tie1 = 0, tie2 = 0;
#pragma unroll
        for (int j = 0; j < 64; ++j) {
            float4 cj = cbox[j];
            float aj = carea[j];
            iou_bit(me1, ar1, cj, aj, j, lo1, hi1, tie1);
            iou_bit(me2, ar2, cj, aj, j, lo2, hi2, tie2);
        }
        u64 w1 = ((u64)hi1 << 32) | lo1;
        u64 w2 = ((u64)hi2 << 32) | lo2;
        if (__builtin_expect(tie1, 0)) w1 = slow_word(me1, ar1, cbox, carea);
        if (__builtin_expect(tie2, 0)) w2 = slow_word(me2, ar2, cbox, carea);
        int d1 = r1 - cb * 64;
        if (d1 >= 0) w1 &= ~((2ULL << d1) - 1ULL);   // keep cols strictly after row
        int d2 = r2 - cb * 64;
        if (d2 >= 0) w2 &= ~((2ULL << d2) - 1ULL);
        dst[r1] = w1;
        dst[r2] = w2;
    } else if (a1) {
        unsigned lo1 = 0, hi1 = 0;
        int tie1 = 0;
#pragma unroll
        for (int j = 0; j < 64; ++j) {
            float4 cj = cbox[j];
            float aj = carea[j];
            iou_bit(me1, ar1, cj, aj, j, lo1, hi1, tie1);
        }
        u64 w1 = ((u64)hi1 << 32) | lo1;
        if (__builtin_expect(tie1, 0)) w1 = slow_word(me1, ar1, cbox, carea);
        int d1 = r1 - cb * 64;
        if (d1 >= 0) w1 &= ~((2ULL << d1) - 1ULL);
        dst[r1] = w1;
    }
}

// ---------------------------------------------------------------------------
// DPP all-reduce OR within a 16-lane row (quad xor1, xor2, half-mirror,
// mirror). Every lane ends with the OR of its 16-lane row. VALU-latency
// chain (~8 cy/level) instead of ds_bpermute (~120 cy/level).
// ---------------------------------------------------------------------------
__device__ __forceinline__ unsigned dpp_or16(unsigned v) {
    v |= (unsigned)__builtin_amdgcn_update_dpp(0, (int)v, 0xB1, 0xF, 0xF, true);   // quad_perm {1,0,3,2}
    v |= (unsigned)__builtin_amdgcn_update_dpp(0, (int)v, 0x4E, 0xF, 0xF, true);   // quad_perm {2,3,0,1}
    v |= (unsigned)__builtin_amdgcn_update_dpp(0, (int)v, 0x141, 0xF, 0xF, true);  // row_half_mirror
    v |= (unsigned)__builtin_amdgcn_update_dpp(0, (int)v, 0x140, 0xF, 0xF, true);  // row_mirror
    return v;
}

__device__ __forceinline__ unsigned wave_or_from_rows(unsigned rowred) {
    unsigned a = (unsigned)__builtin_amdgcn_readlane((int)rowred, 0) |
                 (unsigned)__builtin_amdgcn_readlane((int)rowred, 16);
    unsigned c = (unsigned)__builtin_amdgcn_readlane((int)rowred, 32) |
                 (unsigned)__builtin_amdgcn_readlane((int)rowred, 48);
    return a | c;
}

// ---------------------------------------------------------------------------
// Resumable sequential scan stage: processes column blocks [rb0, rb1).
// State persisted in workspace: picks_g (global pick rows), kcnt, done.
// Round-7 rewrite of the inner machinery (semantics identical):
//  - greedy resolution is SCALAR: total is readfirstlane'd, per-pick row
//    fetched with v_readlane (SGPR-indexed) -> ~30 cy/pick vs ~300 cy for
//    the old 2x ds_bpermute chain.
//  - the 6-level bpermute butterfly OR-reduce is replaced by 4 DPP levels
//    + readlanes + 4 LDS broadcast reads (~100 cy vs ~720 cy per block).
//  - the bulk pick-gather for block rb+1 (8 u64 slots, covers K<=2048) is
//    ISSUED right after B1 of block rb and consumed at the top of rb+1, so
//    its memory latency hides under wave0's greedy + the barrier drain.
//    New picks' next-slab words are loaded by the picking lanes themselves
//    (delta) and folded into the next reduce; myrow/mybox prefetch one
//    block ahead.
// ---------------------------------------------------------------------------
__global__ __launch_bounds__(256) void scan_nms(const float4* __restrict__ sbox,
                                                const u64* __restrict__ bitmap,
                                                float* __restrict__ out,
                                                int* __restrict__ picks_g,
                                                int* __restrict__ kcnt,
                                                int* __restrict__ done,
                                                int rb0, int rb1) {
    int b = blockIdx.x;
    if (done[b]) return;
    int tid = threadIdx.x;
    int lane = tid & 63;
    int wv = tid >> 6;
    __shared__ int picks_lds[POST_TOPN];   // 8 KB
    __shared__ u64 s_partial[4];
    __shared__ int s_K;

    int* pg = picks_g + (size_t)b * POST_TOPN;
    int K0 = kcnt[b];
    if (tid == 0) s_K = K0;
    for (int t = tid; t < K0; t += 256) picks_lds[t] = pg[t];
    __syncthreads();

    const u64* bm = bitmap + (size_t)b * TRI_WORDS;
    const float4* sbb = sbox + (size_t)b * PADN;

    // ---- prologue: un-pipelined prefetch for block rb0 ----
    u64 pf0 = 0, pf1 = 0, pf2 = 0, pf3 = 0, pf4 = 0, pf5 = 0, pf6 = 0, pf7 = 0;
    u64 myrow = 0, delta = 0;
    float4 mybox = make_float4(0.f, 0.f, 0.f, 0.f);
    {
        const u64* slab = bm + (size_t)32 * rb0 * (rb0 + 1);
        int t0 = tid;
        if (t0 < K0)        pf0 = slab[picks_lds[t0]];
        if (t0 + 256 < K0)  pf1 = slab[picks_lds[t0 + 256]];
        if (t0 + 512 < K0)  pf2 = slab[picks_lds[t0 + 512]];
        if (t0 + 768 < K0)  pf3 = slab[picks_lds[t0 + 768]];
        if (t0 + 1024 < K0) pf4 = slab[picks_lds[t0 + 1024]];
        if (t0 + 1280 < K0) pf5 = slab[picks_lds[t0 + 1280]];
        if (t0 + 1536 < K0) pf6 = slab[picks_lds[t0 + 1536]];
        if (t0 + 1792 < K0) pf7 = slab[picks_lds[t0 + 1792]];
        if (wv == 0) {
            myrow = slab[rb0 * 64 + lane];
            mybox = sbb[rb0 * 64 + lane];
        }
    }

    for (int rb = rb0; rb < rb1; ++rb) {
        int K = s_K;                       // uniform (post-barrier)
        if (K >= POST_TOPN) break;
        int base = rb * 64;
        const u64* slab_next = bm + (size_t)32 * (rb + 1) * (rb + 2);
        bool havenext = (rb + 1 < rb1);

        // consume prefetched suppression words
        u64 sup = ((pf0 | pf1) | (pf2 | pf3)) | ((pf4 | pf5) | (pf6 | pf7));
        sup |= delta;                       // wave0's new-pick words (0 elsewhere)
        // intra-wave DPP OR-reduce -> wave total
        unsigned rlo = dpp_or16((unsigned)(sup & 0xffffffffULL));
        unsigned rhi = dpp_or16((unsigned)(sup >> 32));
        unsigned wlo = wave_or_from_rows(rlo);
        unsigned whi = wave_or_from_rows(rhi);
        if (lane == 0) s_partial[wv] = ((u64)whi << 32) | wlo;
        __syncthreads();                   // B1

        // issue bulk prefetch for rb+1 over picks [0,K) -- consumed next iter;
        // latency hides under wave0's greedy below + the B2 drain.
        delta = 0;
        if (havenext) {
            int t0 = tid;
            pf0 = (t0 < K)        ? slab_next[picks_lds[t0]]        : 0;
            pf1 = (t0 + 256 < K)  ? slab_next[picks_lds[t0 + 256]]  : 0;
            pf2 = (t0 + 512 < K)  ? slab_next[picks_lds[t0 + 512]]  : 0;
            pf3 = (t0 + 768 < K)  ? slab_next[picks_lds[t0 + 768]]  : 0;
            pf4 = (t0 + 1024 < K) ? slab_next[picks_lds[t0 + 1024]] : 0;
            pf5 = (t0 + 1280 < K) ? slab_next[picks_lds[t0 + 1280]] : 0;
            pf6 = (t0 + 1536 < K) ? slab_next[picks_lds[t0 + 1536]] : 0;
            pf7 = (t0 + 1792 < K) ? slab_next[picks_lds[t0 + 1792]] : 0;
        } else {
            pf0 = pf1 = pf2 = pf3 = pf4 = pf5 = pf6 = pf7 = 0;
        }

        if (wv == 0) {
            u64 t4 = (s_partial[0] | s_partial[1]) | (s_partial[2] | s_partial[3]);
            if (rb == NBLK - 1) t4 |= 0xFFFFFFFF00000000ULL;   // pad rows >= 12000
            // scalarize; greedy runs on the scalar pipe with readlane row fetch
            unsigned tlo = (unsigned)__builtin_amdgcn_readfirstlane((int)(t4 & 0xffffffffULL));
            unsigned thi = (unsigned)__builtin_amdgcn_readfirstlane((int)(t4 >> 32));
            u64 alive = ~(((u64)thi << 32) | tlo);
            int mrl = (int)(myrow & 0xffffffffULL);
            int mrh = (int)(myrow >> 32);
            u64 picks = 0;
            u64 cur = alive;
            while (cur) {
                int i = (int)__builtin_ctzll(cur);
                picks |= 1ULL << i;
                unsigned rl = (unsigned)__builtin_amdgcn_readlane(mrl, i);
                unsigned rh = (unsigned)__builtin_amdgcn_readlane(mrh, i);
                u64 row = ((u64)rh << 32) | rl;
                alive &= ~row;
                cur = alive & ~((2ULL << i) - 1ULL);
            }
            int avail = POST_TOPN - K;
            int np = __popcll(picks);
            while (np > avail) {                       // truncate latest picks
                picks &= ~(1ULL << (63 - __clzll(picks)));
                --np;
            }
            int c = lane;
            bool ipick = ((picks >> c) & 1ULL) != 0;
            if (ipick) {
                int rank = __popcll(picks & ((1ULL << c) - 1ULL));
                int gi = base + c;
                picks_lds[K + rank] = gi;
                pg[K + rank] = gi;
                float* o = out + ((size_t)b * POST_TOPN + K + rank) * 5;
                o[0] = (float)b; o[1] = mybox.x; o[2] = mybox.y; o[3] = mybox.z; o[4] = mybox.w;
            }
            if (havenext) {
                // picking lanes fetch their own next-slab word (folded into
                // next iteration's reduce); prefetch next diagonal row + box
                if (ipick) delta = slab_next[base + c];
                myrow = slab_next[(rb + 1) * 64 + lane];
                mybox = sbb[(rb + 1) * 64 + lane];
            }
            if (c == 0) s_K = K + np;
        }
        __syncthreads();                   // B2 (drains wave0's prefetches too)
    }

    int K = s_K;
    if (K >= POST_TOPN || rb1 >= NBLK) {
        for (int r = K + tid; r < POST_TOPN; r += 256) {
            float* o = out + ((size_t)b * POST_TOPN + r) * 5;
            o[0] = 0.0f; o[1] = 0.0f; o[2] = 0.0f; o[3] = 0.0f; o[4] = 0.0f;
        }
        if (tid == 0) done[b] = 1;
    }
    if (tid == 0) kcnt[b] = K;
}

// ---------------------------------------------------------------------------
// Fallback (round-2) NMS kernel — used only if ws_size can't hold the bitmap.
// ---------------------------------------------------------------------------
__global__ __launch_bounds__(1024) void nms_kernel(const float* __restrict__ boxes,
                                                   const u64* __restrict__ keys,
                                                   float* __restrict__ out,
                                                   int N) {
#pragma clang fp contract(off)
    __shared__ float4 kbox[POST_TOPN];
    __shared__ float kar[POST_TOPN];
    __shared__ float4 cbox[64];
    __shared__ float car_s[64];
    __shared__ int supp[64];
    __shared__ int s_cnt;

    int b = blockIdx.x;
    int tid = threadIdx.x;
    const u64* kb = keys + (size_t)b * SORTN;
    const float* bb = boxes + (size_t)b * N * 4;

    if (tid == 0) s_cnt = 0;
    __syncthreads();

    for (int start = 0; start < PRE_TOPN; start += 64) {
        int K = s_cnt;
        if (K >= POST_TOPN) break;
        int csize = min(64, PRE_TOPN - start);

        if (tid < 64) {
            int c = tid;
            if (c < csize) {
                u64 key = kb[start + c];
                int n = (int)(unsigned int)(key & 0xFFFFFFFFULL);
                const float* p = bb + (size_t)n * 4;
                float x1 = p[0], y1 = p[1], x2 = p[2], y2 = p[3];
                cbox[c] = make_float4(x1, y1, x2, y2);
                car_s[c] = ((x2 - x1) + 1.0f) * ((y2 - y1) + 1.0f);
            }
            supp[c] = 0;
        }
        __syncthreads();

        {
            int c = tid & 63;
            int sl = tid >> 6;
            if (c < csize) {
                float4 me = cbox[c];
                float ar = car_s[c];
                int flag = 0;
                for (int kk = sl; kk < K; kk += 16) {
                    float4 k0 = kbox[kk];
                    float a0 = kar[kk];
                    float xx1 = fmaxf(k0.x, me.x);
                    float yy1 = fmaxf(k0.y, me.y);
                    float xx2 = fminf(k0.z, me.z);
                    float yy2 = fminf(k0.w, me.w);
                    float w0 = fmaxf((xx2 - xx1) + 1.0f, 0.0f);
                    float h0 = fmaxf((yy2 - yy1) + 1.0f, 0.0f);
                    float inter0 = w0 * h0;
                    float iou0 = inter0 / ((a0 + ar) - inter0);
                    if (iou0 > 0.7f) { flag = 1; break; }
                }
                if (flag) supp[c] = 1;
            }
        }
        __syncthreads();

        if (tid < 64) {
            int c = tid;
            bool alive = (c < csize) && (supp[c] == 0);
            float4 me = cbox[c];
            float ar = car_s[c];
            int cnt = K;
            u64 m = __ballot(alive);
            while (m != 0 && cnt < POST_TOPN) {
                int i = __ffsll((unsigned long long)m) - 1;
                float ix1 = __shfl(me.x, i);
                float iy1 = __shfl(me.y, i);
                float ix2 = __shfl(me.z, i);
                float iy2 = __shfl(me.w, i);
                float iar = __shfl(ar, i);
                if (c == i) {
                    kbox[cnt] = me;
                    kar[cnt] = ar;
                    float* o = out + ((size_t)b * POST_TOPN + cnt) * 5;
                    o[0] = (float)b; o[1] = me.x; o[2] = me.y; o[3] = me.z; o[4] = me.w;
                }
                if (alive && c > i) {
                    float xx1 = fmaxf(ix1, me.x);
                    float yy1 = fmaxf(iy1, me.y);
                    float xx2 = fminf(ix2, me.z);
                    float yy2 = fminf(iy2, me.w);
                    float w = fmaxf((xx2 - xx1) + 1.0f, 0.0f);
                    float h = fmaxf((yy2 - yy1) + 1.0f, 0.0f);
                    float inter = w * h;
                    float iou = inter / ((iar + ar) - inter);
                    if (iou > 0.7f) alive = false;
                }
                cnt++;
                m = __ballot(alive);
                u64 clearmask = (2ULL << i) - 1ULL;
                m &= ~clearmask;
            }
            if (c == 0) s_cnt = cnt;
        }
        __syncthreads();
    }

    __syncthreads();
    int K = s_cnt;
    for (int r = K + tid; r < POST_TOPN; r += (int)blockDim.x) {
        float* o = out + ((size_t)b * POST_TOPN + r) * 5;
        o[0] = 0.0f; o[1] = 0.0f; o[2] = 0.0f; o[3] = 0.0f; o[4] = 0.0f;
    }
}

// ---------------------------------------------------------------------------
extern "C" void kernel_launch(void* const* d_in, const int* in_sizes, int n_in,
                              void* d_out, int out_size, void* d_ws, size_t ws_size,
                              hipStream_t stream) {
    const float* anchors = (const float*)d_in[0];
    const float* deltas  = (const float*)d_in[1];
    const float* scores  = (const float*)d_in[2];
    float* out = (float*)d_out;

    int N = in_sizes[0] / 4;           // 27380
    int B = in_sizes[2] / N;           // 8

    size_t off = 0;
    auto take = [&](size_t bytes) { size_t o = off; off = (off + bytes + 255) & ~(size_t)255; return o; };
    size_t boxesOff  = take((size_t)B * N * 4 * sizeof(float));
    size_t keysOff   = take((size_t)B * SORTN * sizeof(u64));
    size_t sboxOff   = take((size_t)B * PADN * sizeof(float4));
    size_t bitmapOff = take((size_t)B * TRI_WORDS * sizeof(u64));
    size_t picksOff  = take((size_t)B * POST_TOPN * sizeof(int));
    size_t kcntOff   = take((size_t)B * sizeof(int));
    size_t doneOff   = take((size_t)B * sizeof(int));
    bool bitmap_path = (off <= ws_size);

    float* boxes = (float*)((char*)d_ws + boxesOff);
    u64*   keys  = (u64*)((char*)d_ws + keysOff);
    int* picks_g = bitmap_path ? (int*)((char*)d_ws + picksOff) : nullptr;
    int* kcnt    = bitmap_path ? (int*)((char*)d_ws + kcntOff)  : nullptr;
    int* done    = bitmap_path ? (int*)((char*)d_ws + doneOff)  : nullptr;

    dim3 g1((unsigned)((SORTN + 255) / 256), (unsigned)B);
    decode_pack<<<g1, 256, 0, stream>>>(anchors, deltas, scores, boxes, keys, kcnt, done, N);

    int ntiles = B * NTILE;
    bitonic_local_sort<<<ntiles, 1024, 0, stream>>>(keys);
    int gsteps = B * (SORTN / 2) / 256;
    bitonic_global_step<<<gsteps, 256, 0, stream>>>(keys, 2 * TILE, TILE);
    bitonic_local_merge<<<ntiles, 1024, 0, stream>>>(keys, 2 * TILE);
    bitonic_global_step<<<gsteps, 256, 0, stream>>>(keys, 4 * TILE, 2 * TILE);
    bitonic_global_step<<<gsteps, 256, 0, stream>>>(keys, 4 * TILE, TILE);
    bitonic_local_merge<<<ntiles, 1024, 0, stream>>>(keys, 4 * TILE);

    if (bitmap_path) {
        float4* sbox = (float4*)((char*)d_ws + sboxOff);
        u64* bitmap  = (u64*)((char*)d_ws + bitmapOff);
        dim3 gg((unsigned)((PADN + 255) / 256), (unsigned)B);
        gather_sorted<<<gg, 256, 0, stream>>>(boxes, keys, sbox, N);

        // Progressive build/scan: each scan stage consumes the column blocks
        // built so far; once a batch reaches 2000 picks its done[] flag makes
        // all later build/scan blocks exit immediately. Final stage always
        // reaches NBLK, so correctness is independent of the pick rate.
        const int seg[6] = {0, 48, 64, 88, 120, NBLK};
        for (int s = 0; s < 5; ++s) {
            int c0 = seg[s], c1 = seg[s + 1];
            unsigned gy = (unsigned)(((c1 - 1) >> 3) + 1);   // 512-row chunks
            dim3 gb((unsigned)(c1 - c0), gy, (unsigned)B);
            build_bitmap<<<gb, 256, 0, stream>>>(sbox, bitmap, done, c0);
            scan_nms<<<B, 256, 0, stream>>>(sbox, bitmap, out, picks_g, kcnt, done, c0, c1);
        }
    } else {
        nms_kernel<<<B, 1024, 0, stream>>>(boxes, keys, out, N);
    }
}

// Round 3
// 350.122 us; speedup vs baseline: 1.8811x; 1.0126x over previous
//
#include <hip/hip_runtime.h>
#include <cmath>

typedef unsigned long long u64;

#define PRE_TOPN 12000
#define POST_TOPN 2000
#define SORTN 32768
#define TILE 8192
#define NTILE (SORTN / TILE)   // 4 tiles per batch
#define NBLK 188               // 64-bit column blocks covering 12032
#define PADN (NBLK * 64)       // 12032
// triangular bitmap: column-block cb stores rows 0..(cb+1)*64-1
// triOff(cb) = 32*cb*(cb+1); total words per batch:
#define TRI_WORDS (32 * (NBLK - 1) * NBLK + NBLK * 64)  // 1,137,024
#define MASK_WORDS 192         // 188 used, padded for safe clamp-free indexing

// ---------------------------------------------------------------------------
// Kernel 1: decode boxes (exact fp32 op order, no FMA contraction, exp via
// double) and pack sort keys. key = (~score_bits)<<32 | idx.
// Also resets the per-batch NMS progress state (kcnt/done) for this launch.
// ---------------------------------------------------------------------------
__global__ void decode_pack(const float* __restrict__ anchors,
                            const float* __restrict__ deltas,
                            const float* __restrict__ scores,
                            float* __restrict__ boxes,
                            u64* __restrict__ keys,
                            int* __restrict__ kcnt,
                            int* __restrict__ done,
                            int N) {
#pragma clang fp contract(off)
    int n = blockIdx.x * blockDim.x + threadIdx.x;
    int b = blockIdx.y;
    if (kcnt != nullptr && blockIdx.x == 0 && threadIdx.x == 0) {
        kcnt[b] = 0;
        done[b] = 0;
    }
    if (n >= SORTN) return;
    u64* kb = keys + (size_t)b * SORTN;
    if (n < N) {
        float a0 = anchors[n * 4 + 0];
        float a1 = anchors[n * 4 + 1];
        float a2 = anchors[n * 4 + 2];
        float a3 = anchors[n * 4 + 3];
        float w = (a2 - a0) + 1.0f;
        float h = (a3 - a1) + 1.0f;
        float cx = a0 + 0.5f * w;
        float cy = a1 + 0.5f * h;
        const float* d = deltas + ((size_t)b * N + n) * 4;
        float dx = d[0], dy = d[1], dw = d[2], dh = d[3];
        float px = cx + w * dx;
        float py = cy + h * dy;
        float pw = (float)::exp((double)dw) * w;
        float ph = (float)::exp((double)dh) * h;
        float* bb = boxes + ((size_t)b * N + n) * 4;
        bb[0] = px - 0.5f * pw;
        bb[1] = py - 0.5f * ph;
        bb[2] = px + 0.5f * (pw - 2.0f);
        bb[3] = py + 0.5f * (ph - 2.0f);
        unsigned int sb = __float_as_uint(scores[(size_t)b * N + n]);
        kb[n] = ((u64)(~sb) << 32) | (u64)(unsigned int)n;
    } else {
        kb[n] = ~0ULL;
    }
}

// ---------------------------------------------------------------------------
// Hybrid bitonic sort (unchanged).
// ---------------------------------------------------------------------------
__global__ __launch_bounds__(1024) void bitonic_local_sort(u64* __restrict__ keys) {
    __shared__ u64 sk[TILE];
    int tile = blockIdx.x;
    u64* kb = keys + (size_t)tile * TILE;
    int base = (tile % NTILE) * TILE;
    for (int i = threadIdx.x; i < TILE; i += 1024) sk[i] = kb[i];
    __syncthreads();
    for (int k = 2; k <= TILE; k <<= 1) {
        for (int j = k >> 1; j > 0; j >>= 1) {
            for (int t = threadIdx.x; t < TILE / 2; t += 1024) {
                int i = ((t & ~(j - 1)) << 1) | (t & (j - 1));
                int ixj = i | j;
                u64 a = sk[i];
                u64 c = sk[ixj];
                bool up = (((base + i) & k) == 0);
                if ((a > c) == up) { sk[i] = c; sk[ixj] = a; }
            }
            __syncthreads();
        }
    }
    for (int i = threadIdx.x; i < TILE; i += 1024) kb[i] = sk[i];
}

__global__ void bitonic_global_step(u64* __restrict__ keys, int k, int j) {
    int t = blockIdx.x * blockDim.x + threadIdx.x;
    int b = t / (SORTN / 2);
    int s = t % (SORTN / 2);
    int i = ((s & ~(j - 1)) << 1) | (s & (j - 1));
    int ixj = i | j;
    u64* kb = keys + (size_t)b * SORTN;
    u64 a = kb[i];
    u64 c = kb[ixj];
    bool up = ((i & k) == 0);
    if ((a > c) == up) { kb[i] = c; kb[ixj] = a; }
}

__global__ __launch_bounds__(1024) void bitonic_local_merge(u64* __restrict__ keys, int k) {
    __shared__ u64 sk[TILE];
    int tile = blockIdx.x;
    u64* kb = keys + (size_t)tile * TILE;
    int base = (tile % NTILE) * TILE;
    bool up = ((base & k) == 0);
    for (int i = threadIdx.x; i < TILE; i += 1024) sk[i] = kb[i];
    __syncthreads();
    for (int j = TILE / 2; j > 0; j >>= 1) {
        for (int t = threadIdx.x; t < TILE / 2; t += 1024) {
            int i = ((t & ~(j - 1)) << 1) | (t & (j - 1));
            int ixj = i | j;
            u64 a = sk[i];
            u64 c = sk[ixj];
            if ((a > c) == up) { sk[i] = c; sk[ixj] = a; }
        }
        __syncthreads();
    }
    for (int i = threadIdx.x; i < TILE; i += 1024) kb[i] = sk[i];
}

// ---------------------------------------------------------------------------
// Gather sorted top-PADN boxes. Pad rows get far-away degenerate boxes.
// ---------------------------------------------------------------------------
__global__ void gather_sorted(const float* __restrict__ boxes,
                              const u64* __restrict__ keys,
                              float4* __restrict__ sbox, int N) {
    int r = blockIdx.x * 256 + threadIdx.x;
    int b = blockIdx.y;
    if (r >= PADN) return;
    float4 v;
    if (r < PRE_TOPN) {
        u64 key = keys[(size_t)b * SORTN + r];
        int n = (int)(unsigned)(key & 0xffffffffULL);
        v = ((const float4*)boxes)[(size_t)b * N + n];
    } else {
        v = make_float4(-4e8f, -4e8f, -4e8f, -4e8f);
    }
    sbox[(size_t)b * PADN + r] = v;
}

// ---------------------------------------------------------------------------
// Exact-f32 suppression predicate (bit-identical to the f64 reference test).
// ---------------------------------------------------------------------------
__device__ __forceinline__ void iou_bit(float4 me, float ar, float4 cj, float aj,
                                        int j, unsigned& lo, unsigned& hi, int& tie) {
#pragma clang fp contract(off)
    float xx1 = fmaxf(me.x, cj.x);
    float yy1 = fmaxf(me.y, cj.y);
    float xx2 = fminf(me.z, cj.z);
    float yy2 = fminf(me.w, cj.w);
    float w = fmaxf((xx2 - xx1) + 1.0f, 0.0f);
    float h = fmaxf((yy2 - yy1) + 1.0f, 0.0f);
    float inter = w * h;
    float un = (ar + aj) - inter;
    float t = __builtin_fmaf(-0.7f, un, inter);
    float u25 = un * 0x1p-25f;
    unsigned sup = (t > u25) ? 1u : 0u;
    tie |= (t == u25) ? 1 : 0;
    if (j < 32) lo |= sup << j;
    else        hi |= sup << (j - 32);
}

__device__ __attribute__((noinline)) u64 slow_word(float4 me, float ar,
                                                   const float4* cbox,
                                                   const float* carea) {
#pragma clang fp contract(off)
    const double MD = (double)0.7f + 0x1p-25;   // exact midpoint multiplier
    u64 word = 0;
    for (int j = 0; j < 64; ++j) {
        float4 cj = cbox[j];
        float aj = carea[j];
        float xx1 = fmaxf(me.x, cj.x);
        float yy1 = fmaxf(me.y, cj.y);
        float xx2 = fminf(me.z, cj.z);
        float yy2 = fminf(me.w, cj.w);
        float w = fmaxf((xx2 - xx1) + 1.0f, 0.0f);
        float h = fmaxf((yy2 - yy1) + 1.0f, 0.0f);
        float inter = w * h;
        float un = (ar + aj) - inter;
        bool sup = ((double)inter >= MD * (double)un);
        word |= ((u64)sup) << j;
    }
    return word;
}

// ---------------------------------------------------------------------------
// Build suppression bitmap for column blocks [cb0, cb0+gridDim.x).
// ---------------------------------------------------------------------------
__global__ __launch_bounds__(256) void build_bitmap(const float4* __restrict__ sbox,
                                                    u64* __restrict__ bitmap,
                                                    const int* __restrict__ done,
                                                    int cb0) {
    int cb = cb0 + blockIdx.x;  // column block
    int chunk = blockIdx.y;     // row chunk (512 rows)
    int b = blockIdx.z;
    if (done[b]) return;
    if (chunk * 8 > cb) return; // chunk's first row >= (cb+1)*64 -> empty
    int tid = threadIdx.x;
    int lim = (cb + 1) * 64;    // rows stored in this slab: [0, lim)

    __shared__ float4 cbox[64];
    __shared__ float carea[64];
    const float4* sb = sbox + (size_t)b * PADN;
    if (tid < 64) {
        float4 c4 = sb[cb * 64 + tid];
        cbox[tid] = c4;
        carea[tid] = ((c4.z - c4.x) + 1.0f) * ((c4.w - c4.y) + 1.0f);
    }
    int r1 = chunk * 512 + tid;
    int r2 = r1 + 256;
    bool a1 = (r1 < lim);
    bool a2 = (r2 < lim);
    float4 me1 = sb[r1];
    float4 me2 = me1;
    if (a2) me2 = sb[r2];
    float ar1 = ((me1.z - me1.x) + 1.0f) * ((me1.w - me1.y) + 1.0f);
    float ar2 = ((me2.z - me2.x) + 1.0f) * ((me2.w - me2.y) + 1.0f);
    __syncthreads();

    u64* dst = bitmap + (size_t)b * TRI_WORDS + (size_t)32 * cb * (cb + 1);
    if (a2) {
        unsigned lo1 = 0, hi1 = 0, lo2 = 0, hi2 = 0;
        int tie1 = 0, tie2 = 0;
#pragma unroll
        for (int j = 0; j < 64; ++j) {
            float4 cj = cbox[j];
            float aj = carea[j];
            iou_bit(me1, ar1, cj, aj, j, lo1, hi1, tie1);
            iou_bit(me2, ar2, cj, aj, j, lo2, hi2, tie2);
        }
        u64 w1 = ((u64)hi1 << 32) | lo1;
        u64 w2 = ((u64)hi2 << 32) | lo2;
        if (__builtin_expect(tie1, 0)) w1 = slow_word(me1, ar1, cbox, carea);
        if (__builtin_expect(tie2, 0)) w2 = slow_word(me2, ar2, cbox, carea);
        int d1 = r1 - cb * 64;
        if (d1 >= 0) w1 &= ~((2ULL << d1) - 1ULL);
        int d2 = r2 - cb * 64;
        if (d2 >= 0) w2 &= ~((2ULL << d2) - 1ULL);
        dst[r1] = w1;
        dst[r2] = w2;
    } else if (a1) {
        unsigned lo1 = 0, hi1 = 0;
        int tie1 = 0;
#pragma unroll
        for (int j = 0; j < 64; ++j) {
            float4 cj = cbox[j];
            float aj = carea[j];
            iou_bit(me1, ar1, cj, aj, j, lo1, hi1, tie1);
        }
        u64 w1 = ((u64)hi1 << 32) | lo1;
        if (__builtin_expect(tie1, 0)) w1 = slow_word(me1, ar1, cbox, carea);
        int d1 = r1 - cb * 64;
        if (d1 >= 0) w1 &= ~((2ULL << d1) - 1ULL);
        dst[r1] = w1;
    }
}

// ---------------------------------------------------------------------------
// DPP all-reduce OR within a 16-lane row; wave total via readlanes.
// ---------------------------------------------------------------------------
__device__ __forceinline__ unsigned dpp_or16(unsigned v) {
    v |= (unsigned)__builtin_amdgcn_update_dpp(0, (int)v, 0xB1, 0xF, 0xF, true);   // quad_perm {1,0,3,2}
    v |= (unsigned)__builtin_amdgcn_update_dpp(0, (int)v, 0x4E, 0xF, 0xF, true);   // quad_perm {2,3,0,1}
    v |= (unsigned)__builtin_amdgcn_update_dpp(0, (int)v, 0x141, 0xF, 0xF, true);  // row_half_mirror
    v |= (unsigned)__builtin_amdgcn_update_dpp(0, (int)v, 0x140, 0xF, 0xF, true);  // row_mirror
    return v;
}

__device__ __forceinline__ unsigned wave_or_from_rows(unsigned rowred) {
    unsigned a = (unsigned)__builtin_amdgcn_readlane((int)rowred, 0) |
                 (unsigned)__builtin_amdgcn_readlane((int)rowred, 16);
    unsigned c = (unsigned)__builtin_amdgcn_readlane((int)rowred, 32) |
                 (unsigned)__builtin_amdgcn_readlane((int)rowred, 48);
    return a | c;
}

// ---------------------------------------------------------------------------
// Coalesced masked stream: OR of slab[p] over all picked rows p < lim_words.
// Pick membership comes from the LDS bitmask (1 bit per row). Called by the
// 192 streamer threads (tid in [64,256)). Dense dwordx4 loads (2 words/lane,
// 384 words per chunk) with 2-deep double-buffered banks so HBM/L2 latency
// is exposed only once. Replaces the old address-divergent pick-gather
// (~2-4 cy/lane TA serialization) with line-rate coalesced streaming.
// ---------------------------------------------------------------------------
__device__ __forceinline__ u64 stream_or(const u64* __restrict__ slab,
                                         const u64* s_mask,
                                         int lim_words, int tid) {
    int st = tid - 64;                 // 0..191
    u64 acc = 0;
    int nch = (lim_words + 383) / 384;
    if (nch <= 0) return 0;

    int wA = st * 2;                   // chunk 0
    u64 a0 = 0, a1 = 0;
    if (wA < lim_words) {
        ulonglong2 v = *reinterpret_cast<const ulonglong2*>(slab + wA);
        a0 = v.x; a1 = v.y;
    }
    int c = 0;
    while (true) {
        // issue chunk c+1 into bank B
        u64 b0 = 0, b1 = 0;
        int wB = 0;
        bool haveB = (c + 1 < nch);
        if (haveB) {
            wB = (c + 1) * 384 + st * 2;
            if (wB < lim_words) {
                ulonglong2 v = *reinterpret_cast<const ulonglong2*>(slab + wB);
                b0 = v.x; b1 = v.y;
            }
        }
        // consume bank A (mask word shared by both rows: wA even)
        {
            u64 m = s_mask[wA >> 6];
            int sh = wA & 63;
            acc |= a0 & (0ULL - ((m >> sh) & 1ULL));
            acc |= a1 & (0ULL - ((m >> (sh + 1)) & 1ULL));
        }
        ++c;
        if (!haveB) break;
        // issue chunk c+1 into bank A
        u64 n0 = 0, n1 = 0;
        int wN = 0;
        bool haveA = (c + 1 < nch);
        if (haveA) {
            wN = (c + 1) * 384 + st * 2;
            if (wN < lim_words) {
                ulonglong2 v = *reinterpret_cast<const ulonglong2*>(slab + wN);
                n0 = v.x; n1 = v.y;
            }
        }
        // consume bank B
        {
            u64 m = s_mask[wB >> 6];
            int sh = wB & 63;
            acc |= b0 & (0ULL - ((m >> sh) & 1ULL));
            acc |= b1 & (0ULL - ((m >> (sh + 1)) & 1ULL));
        }
        ++c;
        if (!haveA) break;
        a0 = n0; a1 = n1; wA = wN;
    }
    return acc;
}

// ---------------------------------------------------------------------------
// Resumable sequential scan stage: processes column blocks [rb0, rb1).
// Round-8 rewrite: the per-block pick-gather is replaced by a pick-bitmask
// (188 u64 in LDS, persisted to pickmask_g across stages) + coalesced masked
// stream of the slab, run by waves 1-3 WHILE wave 0 resolves the greedy.
// Coverage per block rb+1: stream(rows < rb*64, final mask) | delta(rows in
// [rb*64,(rb+1)*64), self-loaded by picking lanes) | myrow (within-block).
// Semantics identical to the round-7 scan.
// ---------------------------------------------------------------------------
__global__ __launch_bounds__(256) void scan_nms(const float4* __restrict__ sbox,
                                                const u64* __restrict__ bitmap,
                                                float* __restrict__ out,
                                                u64* __restrict__ pickmask_g,
                                                int* __restrict__ kcnt,
                                                int* __restrict__ done,
                                                int rb0, int rb1) {
    int b = blockIdx.x;
    if (done[b]) return;
    int tid = threadIdx.x;
    int lane = tid & 63;
    int wv = tid >> 6;
    __shared__ u64 s_pickmask[MASK_WORDS];   // 1.5 KB
    __shared__ u64 s_partial[4];
    __shared__ int s_K;

    u64* pmg = pickmask_g + (size_t)b * MASK_WORDS;
    int K0 = kcnt[b];
    if (tid == 0) s_K = K0;
    if (tid < MASK_WORDS) s_pickmask[tid] = (tid < NBLK && K0 > 0) ? pmg[tid] : 0ULL;
    __syncthreads();

    const u64* bm = bitmap + (size_t)b * TRI_WORDS;
    const float4* sbb = sbox + (size_t)b * PADN;

    // ---- prologue for block rb0 ----
    u64 acc = 0;
    u64 myrow = 0;
    float4 mybox = make_float4(0.f, 0.f, 0.f, 0.f);
    {
        const u64* slab0 = bm + (size_t)32 * rb0 * (rb0 + 1);
        if (wv == 0) {
            myrow = slab0[rb0 * 64 + lane];
            mybox = sbb[rb0 * 64 + lane];
        } else if (rb0 > 0) {
            acc = stream_or(slab0, s_pickmask, rb0 * 64, tid);
        }
    }

    for (int rb = rb0; rb < rb1; ++rb) {
        int K = s_K;                       // uniform (post-barrier)
        if (K >= POST_TOPN) break;
        int base = rb * 64;
        const u64* slab_next = bm + (size_t)32 * (rb + 1) * (rb + 2);
        bool havenext = (rb + 1 < rb1);

        // reduce this block's suppression words (streamed acc | wave0's delta)
        u64 sup = acc;
        unsigned rlo = dpp_or16((unsigned)(sup & 0xffffffffULL));
        unsigned rhi = dpp_or16((unsigned)(sup >> 32));
        unsigned wlo = wave_or_from_rows(rlo);
        unsigned whi = wave_or_from_rows(rhi);
        if (lane == 0) s_partial[wv] = ((u64)whi << 32) | wlo;
        __syncthreads();                   // B1

        if (wv == 0) {
            // early prefetch of next diagonal row+box (independent of picks)
            u64 nrow = 0;
            float4 nbox = make_float4(0.f, 0.f, 0.f, 0.f);
            if (havenext) {
                nrow = slab_next[(rb + 1) * 64 + lane];
                nbox = sbb[(rb + 1) * 64 + lane];
            }
            u64 t4 = (s_partial[0] | s_partial[1]) | (s_partial[2] | s_partial[3]);
            if (rb == NBLK - 1) t4 |= 0xFFFFFFFF00000000ULL;   // pad rows >= 12000
            unsigned tlo = (unsigned)__builtin_amdgcn_readfirstlane((int)(t4 & 0xffffffffULL));
            unsigned thi = (unsigned)__builtin_amdgcn_readfirstlane((int)(t4 >> 32));
            u64 alive = ~(((u64)thi << 32) | tlo);
            int mrl = (int)(myrow & 0xffffffffULL);
            int mrh = (int)(myrow >> 32);
            u64 picks = 0;
            u64 cur = alive;
            while (cur) {
                int i = (int)__builtin_ctzll(cur);
                picks |= 1ULL << i;
                unsigned rl = (unsigned)__builtin_amdgcn_readlane(mrl, i);
                unsigned rh = (unsigned)__builtin_amdgcn_readlane(mrh, i);
                u64 row = ((u64)rh << 32) | rl;
                alive &= ~row;
                cur = alive & ~((2ULL << i) - 1ULL);
            }
            int avail = POST_TOPN - K;
            int np = __popcll(picks);
            while (np > avail) {                       // truncate latest picks
                picks &= ~(1ULL << (63 - __clzll(picks)));
                --np;
            }
            int c = lane;
            bool ipick = ((picks >> c) & 1ULL) != 0;
            if (ipick) {
                int rank = __popcll(picks & ((1ULL << c) - 1ULL));
                float* o = out + ((size_t)b * POST_TOPN + K + rank) * 5;
                o[0] = (float)b; o[1] = mybox.x; o[2] = mybox.y; o[3] = mybox.z; o[4] = mybox.w;
            }
            acc = 0;
            if (havenext && ipick) acc = slab_next[base + c];   // delta rows
            if (c == 0) {
                s_K = K + np;
                s_pickmask[rb] = picks;    // rows base..base+63 membership
            }
            myrow = nrow; mybox = nbox;
        } else {
            // stream rows < rb*64 of slab rb+1 (mask words < rb: final)
            acc = havenext ? stream_or(slab_next, s_pickmask, base, tid) : 0;
        }
        __syncthreads();                   // B2
    }

    // persist pick bitmask for the next stage
    if (tid < NBLK) pmg[tid] = s_pickmask[tid];

    int K = s_K;
    if (K >= POST_TOPN || rb1 >= NBLK) {
        for (int r = K + tid; r < POST_TOPN; r += 256) {
            float* o = out + ((size_t)b * POST_TOPN + r) * 5;
            o[0] = 0.0f; o[1] = 0.0f; o[2] = 0.0f; o[3] = 0.0f; o[4] = 0.0f;
        }
        if (tid == 0) done[b] = 1;
    }
    if (tid == 0) kcnt[b] = K;
}

// ---------------------------------------------------------------------------
// Fallback (round-2) NMS kernel — used only if ws_size can't hold the bitmap.
// ---------------------------------------------------------------------------
__global__ __launch_bounds__(1024) void nms_kernel(const float* __restrict__ boxes,
                                                   const u64* __restrict__ keys,
                                                   float* __restrict__ out,
                                                   int N) {
#pragma clang fp contract(off)
    __shared__ float4 kbox[POST_TOPN];
    __shared__ float kar[POST_TOPN];
    __shared__ float4 cbox[64];
    __shared__ float car_s[64];
    __shared__ int supp[64];
    __shared__ int s_cnt;

    int b = blockIdx.x;
    int tid = threadIdx.x;
    const u64* kb = keys + (size_t)b * SORTN;
    const float* bb = boxes + (size_t)b * N * 4;

    if (tid == 0) s_cnt = 0;
    __syncthreads();

    for (int start = 0; start < PRE_TOPN; start += 64) {
        int K = s_cnt;
        if (K >= POST_TOPN) break;
        int csize = min(64, PRE_TOPN - start);

        if (tid < 64) {
            int c = tid;
            if (c < csize) {
                u64 key = kb[start + c];
                int n = (int)(unsigned int)(key & 0xFFFFFFFFULL);
                const float* p = bb + (size_t)n * 4;
                float x1 = p[0], y1 = p[1], x2 = p[2], y2 = p[3];
                cbox[c] = make_float4(x1, y1, x2, y2);
                car_s[c] = ((x2 - x1) + 1.0f) * ((y2 - y1) + 1.0f);
            }
            supp[c] = 0;
        }
        __syncthreads();

        {
            int c = tid & 63;
            int sl = tid >> 6;
            if (c < csize) {
                float4 me = cbox[c];
                float ar = car_s[c];
                int flag = 0;
                for (int kk = sl; kk < K; kk += 16) {
                    float4 k0 = kbox[kk];
                    float a0 = kar[kk];
                    float xx1 = fmaxf(k0.x, me.x);
                    float yy1 = fmaxf(k0.y, me.y);
                    float xx2 = fminf(k0.z, me.z);
                    float yy2 = fminf(k0.w, me.w);
                    float w0 = fmaxf((xx2 - xx1) + 1.0f, 0.0f);
                    float h0 = fmaxf((yy2 - yy1) + 1.0f, 0.0f);
                    float inter0 = w0 * h0;
                    float iou0 = inter0 / ((a0 + ar) - inter0);
                    if (iou0 > 0.7f) { flag = 1; break; }
                }
                if (flag) supp[c] = 1;
            }
        }
        __syncthreads();

        if (tid < 64) {
            int c = tid;
            bool alive = (c < csize) && (supp[c] == 0);
            float4 me = cbox[c];
            float ar = car_s[c];
            int cnt = K;
            u64 m = __ballot(alive);
            while (m != 0 && cnt < POST_TOPN) {
                int i = __ffsll((unsigned long long)m) - 1;
                float ix1 = __shfl(me.x, i);
                float iy1 = __shfl(me.y, i);
                float ix2 = __shfl(me.z, i);
                float iy2 = __shfl(me.w, i);
                float iar = __shfl(ar, i);
                if (c == i) {
                    kbox[cnt] = me;
                    kar[cnt] = ar;
                    float* o = out + ((size_t)b * POST_TOPN + cnt) * 5;
                    o[0] = (float)b; o[1] = me.x; o[2] = me.y; o[3] = me.z; o[4] = me.w;
                }
                if (alive && c > i) {
                    float xx1 = fmaxf(ix1, me.x);
                    float yy1 = fmaxf(iy1, me.y);
                    float xx2 = fminf(ix2, me.z);
                    float yy2 = fminf(iy2, me.w);
                    float w = fmaxf((xx2 - xx1) + 1.0f, 0.0f);
                    float h = fmaxf((yy2 - yy1) + 1.0f, 0.0f);
                    float inter = w * h;
                    float iou = inter / ((iar + ar) - inter);
                    if (iou > 0.7f) alive = false;
                }
                cnt++;
                m = __ballot(alive);
                u64 clearmask = (2ULL << i) - 1ULL;
                m &= ~clearmask;
            }
            if (c == 0) s_cnt = cnt;
        }
        __syncthreads();
    }

    __syncthreads();
    int K = s_cnt;
    for (int r = K + tid; r < POST_TOPN; r += (int)blockDim.x) {
        float* o = out + ((size_t)b * POST_TOPN + r) * 5;
        o[0] = 0.0f; o[1] = 0.0f; o[2] = 0.0f; o[3] = 0.0f; o[4] = 0.0f;
    }
}

// ---------------------------------------------------------------------------
extern "C" void kernel_launch(void* const* d_in, const int* in_sizes, int n_in,
                              void* d_out, int out_size, void* d_ws, size_t ws_size,
                              hipStream_t stream) {
    const float* anchors = (const float*)d_in[0];
    const float* deltas  = (const float*)d_in[1];
    const float* scores  = (const float*)d_in[2];
    float* out = (float*)d_out;

    int N = in_sizes[0] / 4;           // 27380
    int B = in_sizes[2] / N;           // 8

    size_t off = 0;
    auto take = [&](size_t bytes) { size_t o = off; off = (off + bytes + 255) & ~(size_t)255; return o; };
    size_t boxesOff  = take((size_t)B * N * 4 * sizeof(float));
    size_t keysOff   = take((size_t)B * SORTN * sizeof(u64));
    size_t sboxOff   = take((size_t)B * PADN * sizeof(float4));
    size_t bitmapOff = take((size_t)B * TRI_WORDS * sizeof(u64));
    size_t pmaskOff  = take((size_t)B * MASK_WORDS * sizeof(u64));
    size_t kcntOff   = take((size_t)B * sizeof(int));
    size_t doneOff   = take((size_t)B * sizeof(int));
    bool bitmap_path = (off <= ws_size);

    float* boxes = (float*)((char*)d_ws + boxesOff);
    u64*   keys  = (u64*)((char*)d_ws + keysOff);
    u64* pmask   = bitmap_path ? (u64*)((char*)d_ws + pmaskOff) : nullptr;
    int* kcnt    = bitmap_path ? (int*)((char*)d_ws + kcntOff)  : nullptr;
    int* done    = bitmap_path ? (int*)((char*)d_ws + doneOff)  : nullptr;

    dim3 g1((unsigned)((SORTN + 255) / 256), (unsigned)B);
    decode_pack<<<g1, 256, 0, stream>>>(anchors, deltas, scores, boxes, keys, kcnt, done, N);

    int ntiles = B * NTILE;
    bitonic_local_sort<<<ntiles, 1024, 0, stream>>>(keys);
    int gsteps = B * (SORTN / 2) / 256;
    bitonic_global_step<<<gsteps, 256, 0, stream>>>(keys, 2 * TILE, TILE);
    bitonic_local_merge<<<ntiles, 1024, 0, stream>>>(keys, 2 * TILE);
    bitonic_global_step<<<gsteps, 256, 0, stream>>>(keys, 4 * TILE, 2 * TILE);
    bitonic_global_step<<<gsteps, 256, 0, stream>>>(keys, 4 * TILE, TILE);
    bitonic_local_merge<<<ntiles, 1024, 0, stream>>>(keys, 4 * TILE);

    if (bitmap_path) {
        float4* sbox = (float4*)((char*)d_ws + sboxOff);
        u64* bitmap  = (u64*)((char*)d_ws + bitmapOff);
        dim3 gg((unsigned)((PADN + 255) / 256), (unsigned)B);
        gather_sorted<<<gg, 256, 0, stream>>>(boxes, keys, sbox, N);

        // Progressive build/scan with per-batch done[] cutoff.
        const int seg[6] = {0, 48, 64, 88, 120, NBLK};
        for (int s = 0; s < 5; ++s) {
            int c0 = seg[s], c1 = seg[s + 1];
            unsigned gy = (unsigned)(((c1 - 1) >> 3) + 1);   // 512-row chunks
            dim3 gb((unsigned)(c1 - c0), gy, (unsigned)B);
            build_bitmap<<<gb, 256, 0, stream>>>(sbox, bitmap, done, c0);
            scan_nms<<<B, 256, 0, stream>>>(sbox, bitmap, out, pmask, kcnt, done, c0, c1);
        }
    } else {
        nms_kernel<<<B, 1024, 0, stream>>>(boxes, keys, out, N);
    }
}